// Round 15
// baseline (443.389 us; speedup 1.0000x reference)
//
#include <hip/hip_runtime.h>
#include <cstdint>

// Problem constants
#define Bn   32
#define Cn   256
#define Hn   56
#define Wn   56
#define HWn  (Hn*Wn)           // 3136
#define NPIX (Bn*HWn)          // 100352
#define WELEMS (Cn*Cn*9)       // 589824
#define EPSv 1e-5f

// padded channels-last activation plane: [b][58 rows][58 cols][256 ci] i8
// per-pixel 256B block stored XOR-swizzled: 16B slot s lives at s ^ (padded_col & 15)
#define PR   58
#define PPLANE (PR*PR)         // 3364

// ws layout (floats): [8..80) = 72 per-block |w| partials (plain stores);
// [128..384) = F_SUM; [384..640) = F_SQ (zeroed by pack tail blocks).
#define F_WPART 8
#define F_SUM   128
#define F_SQ    384
#define WPK_OFF  4096              // i8 wpk[kc=36(+4 pad)][co=256][64]
#define WPK_SLOTS 40               // pad: A-prefetch reads kc<=37 (garbage, unused)
#define ACT_OFF  (WPK_OFF + WPK_SLOTS*16384)   // 659456 (16B aligned)
#define ACT_BYTES (Bn*PPLANE*Cn)   // 27553792

// conv LDS region: 3 padded rows x 58 px x 256B = 44544 B (+pad to 45056)
#define STAGE_BYTES 44544

typedef int v4i __attribute__((ext_vector_type(4)));

#define GLOBAL_AS __attribute__((address_space(1)))
#define LDS_AS    __attribute__((address_space(3)))

// ---------------------------------------------------------------------------
// Fused packing kernel — R12-verified version (128-thread blocks).
//   [0,784)    act pack    [784,856) weight repack -> 72 partials
//   [856,913)  halo zeroing    [913,917) BN-stats zero-init
__global__ void pack_all(const float* __restrict__ x,
                         const float* __restrict__ w,
                         float* __restrict__ wsf,
                         uint8_t* __restrict__ wpk,
                         uint8_t* __restrict__ act) {
    if (blockIdx.x < 784) {
        int v = blockIdx.x * 128 + threadIdx.x;   // 0..100351
        int b = v / HWn;
        int p = v - b * HWn;
        int y = p / Wn;
        int xx = p - y * Wn;
        const float* xp = x + (size_t)b * Cn * HWn + p;
        int key = (xx + 1) & 15;
        uint32_t* dst = (uint32_t*)(act + ((size_t)(b * PR + (y + 1)) * PR + (xx + 1)) * 256);
        #pragma unroll
        for (int slot = 0; slot < 16; slot++) {
            uint32_t rr[4];
            #pragma unroll
            for (int cw = 0; cw < 4; cw++) {
                uint32_t r = 0;
                #pragma unroll
                for (int j = 0; j < 4; j++) {
                    uint32_t sgn = __float_as_uint(xp[(size_t)(slot * 16 + cw * 4 + j) * HWn]) >> 31;
                    r |= (sgn ? 0xFFu : 0x01u) << (j * 8);
                }
                rr[cw] = r;
            }
            *(uint4*)(dst + (size_t)((slot ^ key) * 4)) = make_uint4(rr[0], rr[1], rr[2], rr[3]);
        }
    } else if (blockIdx.x < 856) {
        int u = (blockIdx.x - 784) * 128 + threadIdx.x;   // 72*128 = 9216
        int co = u / 36;
        int kc = u - co * 36;
        int t  = kc >> 2;
        int s  = kc & 3;
        const float* wp = w + (size_t)co * 2304 + t;      // OIHW
        uint32_t* dst = (uint32_t*)(wpk + ((size_t)kc * 256 + co) * 64);
        float sabs = 0.0f;
        #pragma unroll
        for (int cw = 0; cw < 16; cw++) {
            uint32_t r = 0;
            #pragma unroll
            for (int j = 0; j < 4; j++) {
                int ci = s * 64 + cw * 4 + j;
                float wv = wp[(size_t)ci * 9];
                sabs += fminf(fabsf(wv), 1.0f);
                r |= ((__float_as_uint(wv) >> 31) ? 0xFFu : 0x01u) << (j * 8);
            }
            dst[cw] = r;
        }
        #pragma unroll
        for (int off = 32; off; off >>= 1) sabs += __shfl_down(sabs, off);
        __shared__ float sh[2];
        if ((threadIdx.x & 63) == 0) sh[threadIdx.x >> 6] = sabs;
        __syncthreads();
        if (threadIdx.x == 0)
            wsf[F_WPART + (blockIdx.x - 784)] = sh[0] + sh[1];
    } else if (blockIdx.x < 913) {
        int hv = (blockIdx.x - 856) * 128 + threadIdx.x;
        int b = hv / 228;
        int r = hv - b * 228;
        int y, xx;
        if (r < 58)       { y = 0;  xx = r; }
        else if (r < 116) { y = 57; xx = r - 58; }
        else { int r2 = r - 116; y = 1 + (r2 >> 1); xx = (r2 & 1) * 57; }
        uint4* d = (uint4*)(act + ((size_t)(b * PR + y) * PR + xx) * 256);
        uint4 z = make_uint4(0, 0, 0, 0);
        #pragma unroll
        for (int i = 0; i < 16; i++) d[i] = z;
    } else {
        int idx = (blockIdx.x - 913) * 128 + threadIdx.x;
        wsf[F_SUM + idx] = 0.0f;
    }
}

// ---------------------------------------------------------------------------
// Binary conv as implicit GEMM on the i8 matrix pipe, LDS-staged B.
// Round-15: 3-blocks/CU occupancy version. Block = (batch, ONE output row):
// stages 3 padded rows = 44.5KB LDS -> 3 blocks/CU (133.6KB) = 12 waves/CU
// = 3 waves/SIMD (vs 2 for all 59.4KB variants). Wave tile stays M=4 frags
// (LDS-reads/MFMA = 0.25 — R6's regression was the 0.5 ratio, removed here);
// N = 56 px padded to 4 frags (8 dead lanes, guarded at store/stats).
// acc[4][4]=64 regs + af depth-2 + bf single ~= 140 unified regs <= 170
// (__launch_bounds__(256,3)). Latency hiding from TLP.
__global__ __launch_bounds__(256, 3) void conv_mfma(
    const uint8_t* __restrict__ act, const uint8_t* __restrict__ wpk,
    const float* __restrict__ x, float* __restrict__ wsf,
    float* __restrict__ out) {
    __shared__ uint4 ldsv[2816];              // 45056 B (44544 used + pad)
    uint8_t* lds = (uint8_t*)ldsv;

    const int tid  = threadIdx.x;
    const int lane = tid & 63;
    const int wid  = tid >> 6;                // 0..3
    const int l15  = lane & 15;
    const int l4   = lane >> 4;               // 0..3

    // XCD-aware swizzle: XCD k gets the contiguous tile range [k*224,(k+1)*224).
    const int bxr = blockIdx.x;               // 0..1791
    const int bx  = (bxr & 7) * 224 + (bxr >> 3);
    const int b   = bx / 56;
    const int y0  = bx - b * 56;              // output image row

    // Stage padded rows y0..y0+2 via async global->LDS DMA: 44 x 1KB chunks
    // (last chunk half-valid: per-lane source clamped into the region; its
    // dest spills into the LDS pad, never read).
    {
        const uint8_t* src = act + ((size_t)(b * PR + y0) * PR) * 256;
        #pragma unroll
        for (int j = 0; j < 11; j++) {
            int c = wid + j * 4;               // 0..43, wave-uniform
            int so = c * 1024 + lane * 16;
            if (so > STAGE_BYTES - 16) so = STAGE_BYTES - 16;
            __builtin_amdgcn_global_load_lds(
                (const GLOBAL_AS uint32_t*)(const void*)(src + so),
                (LDS_AS uint32_t*)(void*)(lds + c * 1024),
                16, 0, 0);
        }
    }

    // A-fragment lane base (co = wid*64 + mi*16 + l15, bytes l4*16)
    const uint8_t* abase = wpk + (wid * 64 + l15) * 64 + l4 * 16;

    // A prologue: depth-2 rotation, kc = 0,1.
    v4i af0[4], af1[4];
    #pragma unroll
    for (int mi = 0; mi < 4; mi++) {
        af0[mi] = *(const v4i*)(abase + (size_t)0 * 16384 + mi * 1024);
        af1[mi] = *(const v4i*)(abase + (size_t)1 * 16384 + mi * 1024);
    }

    // Tap-walk state for t=0 (dh=-1, dw=-1): local row 0, col xx (clamped
    // for the 8 dead lanes; their results are discarded).
    int pixb[4], key[4];
    #pragma unroll
    for (int ni = 0; ni < 4; ni++) {
        int n  = ni * 16 + l15;
        int xx = n < 56 ? n : 55;
        pixb[ni] = xx * 256;
        key[ni]  = xx & 15;
    }

    __syncthreads();   // drains vmcnt(0): DMA chunks + af loads all ready

    v4i acc[4][4] = {};

// STEP: load bf for sub-step S, run 16 MFMAs (priority-boosted) on the
// resident AF buffer, then reload AF with K-chunk KN (affine, pad-safe).
#define STEP(S, AF, KN)                                                        \
    {                                                                          \
        v4i bf[4];                                                             \
        _Pragma("unroll")                                                      \
        for (int ni = 0; ni < 4; ni++)                                         \
            bf[ni] = *(const v4i*)(lds + pixb[ni] +                            \
                                   ((((S) * 4 + l4) ^ key[ni]) << 4));         \
        __builtin_amdgcn_s_setprio(1);                                         \
        _Pragma("unroll")                                                      \
        for (int ni = 0; ni < 4; ni++) {                                       \
            _Pragma("unroll")                                                  \
            for (int mi = 0; mi < 4; mi++)                                     \
                acc[mi][ni] = __builtin_amdgcn_mfma_i32_16x16x64_i8(           \
                    AF[mi], bf[ni], acc[mi][ni], 0, 0, 0);                     \
        }                                                                      \
        __builtin_amdgcn_s_setprio(0);                                         \
        {                                                                      \
            const uint8_t* ap = abase + (size_t)(KN) * 16384;                  \
            _Pragma("unroll")                                                  \
            for (int mi = 0; mi < 4; mi++)                                     \
                AF[mi] = *(const v4i*)(ap + mi * 1024);                        \
        }                                                                      \
    }

    #pragma unroll 1
    for (int t = 0; t < 9; t++) {
        const int t4 = t * 4;
        STEP(0, af0, t4 + 2)
        STEP(1, af1, t4 + 3)
        STEP(2, af0, t4 + 4)
        STEP(3, af1, t4 + 5)
        // Tap-walk t -> t+1: dw cycles -1,0,1 (ddw=+1, dtoff=+256), wrapping
        // at t=2,5 (row advance: (58-2)*256); t=8 is the end (no-op).
        const int wrap  = (t == 2 || t == 5);
        const int dtoff = (t == 8) ? 0 : (wrap ? 56 * 256 : 256);
        const int ddw   = (t == 8) ? 0 : (wrap ? -2 : 1);
        #pragma unroll
        for (int ni = 0; ni < 4; ni++) {
            pixb[ni] += dtoff;
            key[ni]   = (key[ni] + ddw) & 15;
        }
    }
#undef STEP

    // mean(|clip(w)|) from the 72 per-block partials (uniform, cheap).
    float wabs = 0.0f;
    #pragma unroll
    for (int j = 0; j < 72; j++) wabs += wsf[F_WPART + j];
    const float mv = wabs * (1.0f / (float)WELEMS);

    const int co_w = wid * 64;
    const int pbase = b * (Cn * HWn) + y0 * 56;

    // Epilogue: scale + shortcut + store + per-channel partial stats.
    // Dead lanes (n >= 56) are excluded from stores and stats.
    float ssum[4][4] = {}, ssq[4][4] = {};
    #pragma unroll
    for (int mi = 0; mi < 4; mi++) {
        #pragma unroll
        for (int ni = 0; ni < 4; ni++) {
            v4i a = acc[mi][ni];
            int n = ni * 16 + l15;
            bool ok = (n < 56);
            #pragma unroll
            for (int q = 0; q < 4; q++) {
                int co = co_w + mi * 16 + l4 * 4 + q;
                size_t idx = (size_t)pbase + (size_t)co * HWn + n;
                if (ok) {
                    float val = fmaf(mv, (float)a[q], x[idx]);
                    out[idx] = val;
                    ssum[mi][q] += val;
                    ssq[mi][q]  += val * val;
                }
            }
        }
    }
    // Reduce across the 16 lanes (l15) sharing each channel, then atomics.
    #pragma unroll
    for (int mi = 0; mi < 4; mi++) {
        #pragma unroll
        for (int q = 0; q < 4; q++) {
            float s = ssum[mi][q], sq = ssq[mi][q];
            #pragma unroll
            for (int off = 1; off < 16; off <<= 1) {
                s  += __shfl_xor(s, off);
                sq += __shfl_xor(sq, off);
            }
            if (l15 == 0) {
                int co = co_w + mi * 16 + l4 * 4 + q;
                atomicAdd(&wsf[F_SUM + co], s);
                atomicAdd(&wsf[F_SQ  + co], sq);
            }
        }
    }
}

// ---------------------------------------------------------------------------
// BN finalize (per-plane, from fused stats) + normalize + ReLU, in place.
__global__ void epilogue_kernel(float* __restrict__ out,
                                const float* __restrict__ wsf,
                                const float* __restrict__ g,
                                const float* __restrict__ bt) {
    int plane = blockIdx.x;   // b*256 + c
    int c = plane & 255;
    const float n = (float)(Bn * HWn);
    float mean = wsf[F_SUM + c] / n;
    float var  = wsf[F_SQ + c] / n - mean * mean;
    float sc = g[c] * rsqrtf(var + EPSv);
    float sh = bt[c] - mean * sc;
    float4* o4 = (float4*)(out + (size_t)plane * HWn);
    for (int i = threadIdx.x; i < HWn / 4; i += 256) {
        float4 v = o4[i];
        v.x = fmaxf(fmaf(v.x, sc, sh), 0.0f);
        v.y = fmaxf(fmaf(v.y, sc, sh), 0.0f);
        v.z = fmaxf(fmaf(v.z, sc, sh), 0.0f);
        v.w = fmaxf(fmaf(v.w, sc, sh), 0.0f);
        o4[i] = v;
    }
}

// ---------------------------------------------------------------------------
extern "C" void kernel_launch(void* const* d_in, const int* in_sizes, int n_in,
                              void* d_out, int out_size, void* d_ws, size_t ws_size,
                              hipStream_t stream) {
    const float* x     = (const float*)d_in[0];
    const float* w     = (const float*)d_in[1];
    const float* gamma = (const float*)d_in[2];
    const float* beta  = (const float*)d_in[3];
    float* out = (float*)d_out;

    float*   wsf = (float*)d_ws;
    uint8_t* wpk = (uint8_t*)d_ws + WPK_OFF;
    uint8_t* act = (uint8_t*)d_ws + ACT_OFF;

    pack_all<<<dim3(917), dim3(128), 0, stream>>>(x, w, wsf, wpk, act);
    conv_mfma<<<dim3(1792), dim3(256), 0, stream>>>(act, wpk, x, wsf, out);
    epilogue_kernel<<<dim3(Bn * Cn), dim3(256), 0, stream>>>(out, wsf, gamma, beta);
}

// Round 16
// 347.525 us; speedup vs baseline: 1.2758x; 1.2758x over previous
//
#include <hip/hip_runtime.h>
#include <cstdint>

// Problem constants
#define Bn   32
#define Cn   256
#define Hn   56
#define Wn   56
#define HWn  (Hn*Wn)           // 3136
#define NPIX (Bn*HWn)          // 100352
#define WELEMS (Cn*Cn*9)       // 589824
#define EPSv 1e-5f

// padded channels-last activation plane: [b][58 rows][58 cols][256 ci] i8
// per-pixel 256B block stored XOR-swizzled: 16B slot s lives at s ^ (padded_col & 15)
#define PR   58
#define PPLANE (PR*PR)         // 3364

// ws layout (floats for wsf): [8..43] = 36 per-block |w| partials (plain
// stores, no init needed); [64..319] = F_SUM; [320..575] = F_SQ (zeroed by
// pack_all blocks 0/1, which complete before conv via stream ordering).
#define F_WPART 8
#define F_SUM   64
#define F_SQ    320
#define WPK_OFF  4096                     // i8 wpk[kc=36][co=256][64]  (A repack)
#define WPK_BYTES WELEMS                  // 589824
#define ACT_OFF  (WPK_OFF + WPK_BYTES)    // 593920 (16B aligned)
#define ACT_BYTES (Bn*PPLANE*Cn)          // 27553792

typedef int v4i __attribute__((ext_vector_type(4)));

#define GLOBAL_AS __attribute__((address_space(1)))
#define LDS_AS    __attribute__((address_space(3)))

// ---------------------------------------------------------------------------
// Fused packing kernel. Activation blocks 0..391 (+ blocks 0/1 zero the BN
// stats accumulators); weight blocks 392..427 store per-block |w| partials.
__global__ void pack_all(const float* __restrict__ x,
                         const float* __restrict__ w,
                         float* __restrict__ wsf,
                         uint8_t* __restrict__ wpk,
                         uint8_t* __restrict__ act) {
    if (blockIdx.x < 392) {
        // --- BN-stats zero-init (replaces the memset dispatch) ---
        if (blockIdx.x < 2)
            wsf[F_SUM + blockIdx.x * 256 + threadIdx.x] = 0.0f;

        int v = blockIdx.x * 256 + threadIdx.x;   // 0..100351
        // --- halo zeroing: 32 batches * 228 border pixels = 7296 ---
        if (v < 7296) {
            int b = v / 228;
            int r = v - b * 228;
            int y, xx;
            if (r < 58)       { y = 0;  xx = r; }
            else if (r < 116) { y = 57; xx = r - 58; }
            else { int r2 = r - 116; y = 1 + (r2 >> 1); xx = (r2 & 1) * 57; }
            uint4* d = (uint4*)(act + ((size_t)(b * PR + y) * PR + xx) * 256);
            uint4 z = make_uint4(0, 0, 0, 0);
            #pragma unroll
            for (int i = 0; i < 16; i++) d[i] = z;
        }
        // --- interior pack with per-pixel XOR swizzle ---
        int b = v / HWn;
        int p = v - b * HWn;
        int y = p / Wn;
        int xx = p - y * Wn;
        const float* xp = x + (size_t)b * Cn * HWn + p;
        int key = (xx + 1) & 15;
        uint32_t* dst = (uint32_t*)(act + ((size_t)(b * PR + (y + 1)) * PR + (xx + 1)) * 256);
        #pragma unroll
        for (int slot = 0; slot < 16; slot++) {
            uint32_t rr[4];
            #pragma unroll
            for (int cw = 0; cw < 4; cw++) {
                uint32_t r = 0;
                #pragma unroll
                for (int j = 0; j < 4; j++) {
                    uint32_t sgn = __float_as_uint(xp[(size_t)(slot * 16 + cw * 4 + j) * HWn]) >> 31;
                    r |= (sgn ? 0xFFu : 0x01u) << (j * 8);
                }
                rr[cw] = r;
            }
            *(uint4*)(dst + (size_t)((slot ^ key) * 4)) = make_uint4(rr[0], rr[1], rr[2], rr[3]);
        }
    } else {
        int u = (blockIdx.x - 392) * 256 + threadIdx.x;   // 36*256 = 9216
        int co = u / 36;
        int kc = u - co * 36;
        int t  = kc >> 2;          // tap
        int s  = kc & 3;           // 64-ci chunk
        const float* wp = w + (size_t)co * 2304 + t;      // OIHW
        uint32_t* dst = (uint32_t*)(wpk + ((size_t)kc * 256 + co) * 64);
        float sabs = 0.0f;
        #pragma unroll
        for (int cw = 0; cw < 16; cw++) {
            uint32_t r = 0;
            #pragma unroll
            for (int j = 0; j < 4; j++) {
                int ci = s * 64 + cw * 4 + j;
                float wv = wp[(size_t)ci * 9];
                sabs += fminf(fabsf(wv), 1.0f);
                r |= ((__float_as_uint(wv) >> 31) ? 0xFFu : 0x01u) << (j * 8);
            }
            dst[cw] = r;
        }
        #pragma unroll
        for (int off = 32; off; off >>= 1) sabs += __shfl_down(sabs, off);
        __shared__ float sh[4];
        if ((threadIdx.x & 63) == 0) sh[threadIdx.x >> 6] = sabs;
        __syncthreads();
        if (threadIdx.x == 0)   // plain store: no atomic, no init required
            wsf[F_WPART + (blockIdx.x - 392)] = sh[0] + sh[1] + sh[2] + sh[3];
    }
}

// ---------------------------------------------------------------------------
// Binary conv as implicit GEMM on the i8 matrix pipe, LDS-staged B.
// Best-measured configuration (round 8, 126.8us conv / 346us total):
// 4 waves, wave tile 64co x 112px, depth-4 A-pipeline af0..af3, single bf,
// runtime t-loop, async global_load_lds staging. Rounds 3-7 and 9-15 probed
// unroll/ILP depth, fp8, occupancy (2/3/4 waves/SIMD), XCD swizzle, setprio,
// N-split, LDS-tile shrink, and cooperative fusion — none beat this point.
__global__ __launch_bounds__(256, 2) void conv_mfma(
    const uint8_t* __restrict__ act, const uint8_t* __restrict__ wpk,
    const float* __restrict__ x, float* __restrict__ wsf,
    float* __restrict__ out) {
    __shared__ uint4 ldsv[3712];              // 59392 B = 58 chunks of 1KB
    uint8_t* lds = (uint8_t*)ldsv;

    const int tid  = threadIdx.x;
    const int lane = tid & 63;
    const int wid  = tid >> 6;                // 0..3
    const int l15  = lane & 15;
    const int l4   = lane >> 4;               // 0..3

    const int bx = blockIdx.x;                // 0..895
    const int b  = bx / 28;
    const int y0 = (bx - b * 28) * 2;         // first output image row

    // Stage padded rows y0..y0+3 via async global->LDS DMA: 58 x 1KB chunks,
    // wave w issues chunks {w, w+4, ...} back-to-back, no waits here.
    {
        const uint8_t* src = act + ((size_t)b * PR + y0) * PR * 256;
        #pragma unroll
        for (int j = 0; j < 15; j++) {
            int c = wid + j * 4;               // wave-uniform
            if (c < 58) {
                __builtin_amdgcn_global_load_lds(
                    (const GLOBAL_AS uint32_t*)(const void*)(src + c * 1024 + lane * 16),
                    (LDS_AS uint32_t*)(void*)(lds + c * 1024),
                    16, 0, 0);
            }
        }
    }

    // A-fragment lane base (co = wid*64 + mi*16 + l15, bytes l4*16)
    const uint8_t* abase = wpk + (wid * 64 + l15) * 64 + l4 * 16;

    // Pipeline prologue: fill the 4 A-buffers with kc = 0..3.
    v4i af0[4], af1[4], af2[4], af3[4];
    #pragma unroll
    for (int mi = 0; mi < 4; mi++) {
        af0[mi] = *(const v4i*)(abase + (size_t)0 * 16384 + mi * 1024);
        af1[mi] = *(const v4i*)(abase + (size_t)1 * 16384 + mi * 1024);
        af2[mi] = *(const v4i*)(abase + (size_t)2 * 16384 + mi * 1024);
        af3[mi] = *(const v4i*)(abase + (size_t)3 * 16384 + mi * 1024);
    }

    // Tap-walking state for t=0 (dh=-1, dw=-1): window corner (r_, c_) local.
    int pixb[7], key[7];
    #pragma unroll
    for (int ni = 0; ni < 7; ni++) {
        int n  = ni * 16 + l15;
        int r_ = n / 56;
        int c_ = n - r_ * 56;
        pixb[ni] = (r_ * 58 + c_) * 256;
        key[ni]  = c_ & 15;
    }

    __syncthreads();   // drains vmcnt(0): LDS-DMA chunks + af loads all ready

    v4i acc[4][7] = {};

// STEP: load bf for sub-step S, run 28 MFMAs on the resident AF buffer,
// then reload AF with K-chunk KCN (distance-4 ahead, clamped tail).
#define STEP(S, AF)                                                            \
    {                                                                          \
        v4i bf[7];                                                             \
        _Pragma("unroll")                                                      \
        for (int ni = 0; ni < 7; ni++)                                         \
            bf[ni] = *(const v4i*)(lds + pixb[ni] +                            \
                                   ((((S) * 4 + l4) ^ key[ni]) << 4));         \
        _Pragma("unroll")                                                      \
        for (int ni = 0; ni < 7; ni++) {                                       \
            _Pragma("unroll")                                                  \
            for (int mi = 0; mi < 4; mi++)                                     \
                acc[mi][ni] = __builtin_amdgcn_mfma_i32_16x16x64_i8(           \
                    AF[mi], bf[ni], acc[mi][ni], 0, 0, 0);                     \
        }                                                                      \
        {                                                                      \
            int kcn = t4 + (S) + 4;                                            \
            kcn = kcn > 35 ? 35 : kcn;   /* tail: redundant reload, unused */  \
            const uint8_t* ap = abase + (size_t)kcn * 16384;                   \
            _Pragma("unroll")                                                  \
            for (int mi = 0; mi < 4; mi++)                                     \
                AF[mi] = *(const v4i*)(ap + mi * 1024);                        \
        }                                                                      \
    }

    #pragma unroll 1
    for (int t = 0; t < 9; t++) {
        const int t4 = t * 4;
        STEP(0, af0)
        STEP(1, af1)
        STEP(2, af2)
        STEP(3, af3)
        // Tap-walk t -> t+1: dw cycles -1,0,1 (ddw=+1, dtoff=+256), wrapping
        // at t=2,5 (ddw=-2, dtoff=(58-2)*256); t=8 is the end (no-op).
        const int wrap  = (t == 2 || t == 5);
        const int dtoff = (t == 8) ? 0 : (wrap ? 56 * 256 : 256);
        const int ddw   = (t == 8) ? 0 : (wrap ? -2 : 1);
        #pragma unroll
        for (int ni = 0; ni < 7; ni++) {
            pixb[ni] += dtoff;
            key[ni]   = (key[ni] + ddw) & 15;
        }
    }
#undef STEP

    // mean(|clip(w)|) from the 36 per-block partials (uniform, cheap).
    float wabs = 0.0f;
    #pragma unroll
    for (int j = 0; j < 36; j++) wabs += wsf[F_WPART + j];
    const float mv = wabs * (1.0f / (float)WELEMS);

    const int co_w = wid * 64;
    const int pbase = b * (Cn * HWn) + y0 * 56;

    // Epilogue: scale + shortcut + store + per-channel partial stats.
    float ssum[4][4] = {}, ssq[4][4] = {};
    #pragma unroll
    for (int mi = 0; mi < 4; mi++) {
        #pragma unroll
        for (int ni = 0; ni < 7; ni++) {
            v4i a = acc[mi][ni];
            #pragma unroll
            for (int q = 0; q < 4; q++) {
                int co = co_w + mi * 16 + l4 * 4 + q;
                size_t idx = (size_t)pbase + (size_t)co * HWn + (ni * 16 + l15);
                float val = fmaf(mv, (float)a[q], x[idx]);
                out[idx] = val;
                ssum[mi][q] += val;
                ssq[mi][q]  += val * val;
            }
        }
    }
    // Reduce across the 16 lanes (l15) sharing each channel, then atomics.
    #pragma unroll
    for (int mi = 0; mi < 4; mi++) {
        #pragma unroll
        for (int q = 0; q < 4; q++) {
            float s = ssum[mi][q], sq = ssq[mi][q];
            #pragma unroll
            for (int off = 1; off < 16; off <<= 1) {
                s  += __shfl_xor(s, off);
                sq += __shfl_xor(sq, off);
            }
            if (l15 == 0) {
                int co = co_w + mi * 16 + l4 * 4 + q;
                atomicAdd(&wsf[F_SUM + co], s);
                atomicAdd(&wsf[F_SQ  + co], sq);
            }
        }
    }
}

// ---------------------------------------------------------------------------
// BN finalize (per-plane, from fused stats) + normalize + ReLU, in place.
__global__ void epilogue_kernel(float* __restrict__ out,
                                const float* __restrict__ wsf,
                                const float* __restrict__ g,
                                const float* __restrict__ bt) {
    int plane = blockIdx.x;   // b*256 + c
    int c = plane & 255;
    const float n = (float)(Bn * HWn);
    float mean = wsf[F_SUM + c] / n;
    float var  = wsf[F_SQ + c] / n - mean * mean;
    float sc = g[c] * rsqrtf(var + EPSv);
    float sh = bt[c] - mean * sc;
    float4* o4 = (float4*)(out + (size_t)plane * HWn);
    for (int i = threadIdx.x; i < HWn / 4; i += 256) {
        float4 v = o4[i];
        v.x = fmaxf(fmaf(v.x, sc, sh), 0.0f);
        v.y = fmaxf(fmaf(v.y, sc, sh), 0.0f);
        v.z = fmaxf(fmaf(v.z, sc, sh), 0.0f);
        v.w = fmaxf(fmaf(v.w, sc, sh), 0.0f);
        o4[i] = v;
    }
}

// ---------------------------------------------------------------------------
extern "C" void kernel_launch(void* const* d_in, const int* in_sizes, int n_in,
                              void* d_out, int out_size, void* d_ws, size_t ws_size,
                              hipStream_t stream) {
    const float* x     = (const float*)d_in[0];
    const float* w     = (const float*)d_in[1];
    const float* gamma = (const float*)d_in[2];
    const float* beta  = (const float*)d_in[3];
    float* out = (float*)d_out;

    float*   wsf = (float*)d_ws;
    uint8_t* wpk = (uint8_t*)d_ws + WPK_OFF;
    uint8_t* act = (uint8_t*)d_ws + ACT_OFF;

    pack_all<<<dim3(428), dim3(256), 0, stream>>>(x, w, wsf, wpk, act);
    conv_mfma<<<dim3(896), dim3(256), 0, stream>>>(act, wpk, x, wsf, out);
    epilogue_kernel<<<dim3(Bn * Cn), dim3(256), 0, stream>>>(out, wsf, gamma, beta);
}